// Round 2
// baseline (4289.705 us; speedup 1.0000x reference)
//
#include <hip/hip_runtime.h>
#include <math.h>

// GCN pipeline, fp32 end-to-end (no fp32 MFMA on CDNA4 -> vector FMA).
// N=50000 nodes, E=400000 edges, IN=128, H=64.
#define N_NODES 50000
#define N_EDGES 400000

__device__ __forceinline__ float lrelu(float v) { return v > 0.0f ? v : 0.01f * v; }

// ---------------- degree / dinv ----------------
__global__ __launch_bounds__(256) void k_deg(const int* __restrict__ dstv,
                                             float* __restrict__ deg) {
  int e = blockIdx.x * 256 + threadIdx.x;
  if (e < N_EDGES) atomicAdd(&deg[dstv[e]], 1.0f);
}

__global__ __launch_bounds__(256) void k_dinv(float* __restrict__ deg) {
  int i = blockIdx.x * 256 + threadIdx.x;
  if (i < N_NODES) deg[i] = rsqrtf(deg[i] + 1.0f);  // +1 = self loop; always > 0
}

// ---------------- generic fp32 GEMM: C[M][Nc] = A[M][K] @ W[K][Nc] ----------------
// tile 128 rows x 64 cols, KB=32. Thread tile 8r x 4c, rows split {tr*4, 64+tr*4}
// so LDS A-reads are 16B-stride (2-way bank alias = free, m136).
__global__ __launch_bounds__(256, 4) void k_gemm(const float* __restrict__ A,
                                                 const float* __restrict__ W,
                                                 float* __restrict__ C,
                                                 int M, int K, int Nc) {
  __shared__ float At[32][128];  // [k][r] 16KB
  __shared__ float Bt[32][64];   // [k][c]  8KB
  const int rb = blockIdx.x * 128, cb = blockIdx.y * 64;
  const int t = threadIdx.x;
  const int tr = t & 15, tc = t >> 4;
  const int rA = tr * 4, rB = 64 + tr * 4, c0 = tc * 4;
  float acc[8][4] = {};
  for (int kb = 0; kb < K; kb += 32) {
    __syncthreads();
    {  // stage A: 128 rows x 32 k (transposed)
      int r = t & 127, kq = t >> 7;  // kq in {0,1}
      int row = rb + r; if (row >= M) row = M - 1;
      const float* ap = A + (size_t)row * K + kb + kq * 16;
#pragma unroll
      for (int u = 0; u < 4; u++) {
        float4 v = *(const float4*)(ap + u * 4);
        At[kq * 16 + u * 4 + 0][r] = v.x;
        At[kq * 16 + u * 4 + 1][r] = v.y;
        At[kq * 16 + u * 4 + 2][r] = v.z;
        At[kq * 16 + u * 4 + 3][r] = v.w;
      }
    }
    {  // stage B: 32 k x 64 cols
#pragma unroll
      for (int j = 0; j < 2; j++) {
        int f = t + j * 256;
        int r = f >> 4, c4 = (f & 15) * 4;
        *(float4*)&Bt[r][c4] = *(const float4*)(W + (size_t)(kb + r) * Nc + cb + c4);
      }
    }
    __syncthreads();
#pragma unroll 8
    for (int k = 0; k < 32; k++) {
      float4 a0 = *(const float4*)&At[k][rA];
      float4 a1 = *(const float4*)&At[k][rB];
      float4 b  = *(const float4*)&Bt[k][c0];
      float av[8] = {a0.x, a0.y, a0.z, a0.w, a1.x, a1.y, a1.z, a1.w};
      float bv[4] = {b.x, b.y, b.z, b.w};
#pragma unroll
      for (int i = 0; i < 8; i++)
#pragma unroll
        for (int j = 0; j < 4; j++)
          acc[i][j] = fmaf(av[i], bv[j], acc[i][j]);
    }
  }
#pragma unroll
  for (int i = 0; i < 4; i++) {
    int r = rb + rA + i;
    if (r < M) {
      float4 v = {acc[i][0], acc[i][1], acc[i][2], acc[i][3]};
      *(float4*)(C + (size_t)r * Nc + cb + c0) = v;
    }
  }
#pragma unroll
  for (int i = 0; i < 4; i++) {
    int r = rb + rB + i;
    if (r < M) {
      float4 v = {acc[4 + i][0], acc[4 + i][1], acc[4 + i][2], acc[4 + i][3]};
      *(float4*)(C + (size_t)r * Nc + cb + c0) = v;
    }
  }
}

// ---------------- edge scatter: out[dst] += xw[src] * dinv[s]*dinv[d] ----------------
template <int F>
__global__ __launch_bounds__(256) void k_scatter(const float* __restrict__ xw,
                                                 const int* __restrict__ srcv,
                                                 const int* __restrict__ dstv,
                                                 const float* __restrict__ dinv,
                                                 float* __restrict__ out) {
  constexpr int FQ = F / 4;
  int idx = blockIdx.x * 256 + threadIdx.x;  // over E*FQ (exact multiple of 256)
  int e = idx / FQ, q = idx - e * FQ;
  int s = srcv[e], d = dstv[e];
  float nrm = dinv[s] * dinv[d];
  float4 v = *(const float4*)(xw + (size_t)s * F + q * 4);
  float* op = out + (size_t)d * F + q * 4;
  atomicAdd(op + 0, v.x * nrm);
  atomicAdd(op + 1, v.y * nrm);
  atomicAdd(op + 2, v.z * nrm);
  atomicAdd(op + 3, v.w * nrm);
}

// ---------------- finish: h = lrelu(h + xw*dinv^2 + b)  (self-loop folded in) ------
template <int F>
__global__ __launch_bounds__(256) void k_fin(float* __restrict__ h,
                                             const float* __restrict__ xw,
                                             const float* __restrict__ dinv,
                                             const float* __restrict__ b) {
  constexpr int FQ = F / 4;
  int idx = blockIdx.x * 256 + threadIdx.x;  // over N*FQ (exact multiple of 256)
  int i = idx / FQ, q = idx - i * FQ;
  float di = dinv[i];
  float sl = di * di;
  float4 v = *(const float4*)(xw + (size_t)i * F + q * 4);
  float4 a = *(const float4*)(h + (size_t)i * F + q * 4);
  const float* bp = b + q * 4;
  float4 r;
  r.x = lrelu(a.x + v.x * sl + bp[0]);
  r.y = lrelu(a.y + v.y * sl + bp[1]);
  r.z = lrelu(a.z + v.z * sl + bp[2]);
  r.w = lrelu(a.w + v.w * sl + bp[3]);
  *(float4*)(h + (size_t)i * F + q * 4) = r;
}

// ---------------- fused edge MLP ----------------
// Per block: 64 edges. Phase1: t1 = combined[64,576] @ Wf1[576,128] via K-chunks of 32,
// gathering h3[src]/h3[dst] and computing edge-encoder cols on the fly.
// Phase2: lrelu(+bf1) -> T1 transposed in LDS. Phase3: common = T1 @ Wf2 + bf2 -> global.
// Output-col split {tc*4, 64+tc*4} keeps phase-1 B-reads at 16B stride (2-way = free).
struct FusedSMem {
  int src[64], dst[64];      // 512 B
  float We[16 * 64];         // 4 KB
  float be[64];              // 256 B
  float T1t[128][68];        // 34 KB, [k][e] transposed, pad 68 -> 2-way phase-3 reads
  union {
    struct { float A[32][64]; float B[32][128]; } p1;  // 8KB + 16KB
  } u;
};  // total 62.75 KB < 64 KB static limit

__global__ __launch_bounds__(256, 2) void k_fused(
    const float* __restrict__ h3, const int* __restrict__ srcv, const int* __restrict__ dstv,
    const float* __restrict__ eattr, const float* __restrict__ Weg, const float* __restrict__ beg,
    const float* __restrict__ Wf1, const float* __restrict__ bf1,
    const float* __restrict__ Wf2g, const float* __restrict__ bf2,
    float* __restrict__ common) {
  __shared__ FusedSMem sm;
  const int t = threadIdx.x;
  const int eb = blockIdx.x * 64;

  if (t < 64) sm.src[t] = srcv[eb + t];
  else if (t < 128) sm.dst[t - 64] = dstv[eb + t - 64];
  else if (t < 192) sm.be[t - 128] = beg[t - 128];
  *(float4*)&sm.We[t * 4] = *(const float4*)(Weg + t * 4);  // 1024 floats
  __syncthreads();

  const int te = t & 15, tc = t >> 4;
  const int e0 = te * 4;
  const int cA = tc * 4, cB = 64 + tc * 4;  // split col halves
  float acc[4][8] = {};  // [edge i][col j: j<4 -> cA+j, j>=4 -> cB+(j-4)]

  for (int ck = 0; ck < 18; ck++) {
    __syncthreads();
    const int kb = ck * 32;
    const int e = t & 63, kq = t >> 6;  // 4 threads per edge, 8 k each
    if (ck < 16) {
      // gather h3 rows (src for ck<8, dst for 8<=ck<16)
      int row = (ck < 8) ? sm.src[e] : sm.dst[e];
      int colb = (ck < 8) ? kb : kb - 256;
      const float* p = h3 + (size_t)row * 256 + colb + kq * 8;
      float4 v0 = *(const float4*)p;
      float4 v1 = *(const float4*)(p + 4);
      float* ac = &sm.u.p1.A[kq * 8][0];
      ac[0 * 64 + e] = v0.x; ac[1 * 64 + e] = v0.y; ac[2 * 64 + e] = v0.z; ac[3 * 64 + e] = v0.w;
      ac[4 * 64 + e] = v1.x; ac[5 * 64 + e] = v1.y; ac[6 * 64 + e] = v1.z; ac[7 * 64 + e] = v1.w;
    } else {
      // edge-encoder columns: enc = lrelu(edge_attr @ We + be)
      float eav[16];
      const float* ep = eattr + (size_t)(eb + e) * 16;
#pragma unroll
      for (int u = 0; u < 4; u++) {
        float4 v = *(const float4*)(ep + u * 4);
        eav[u * 4 + 0] = v.x; eav[u * 4 + 1] = v.y; eav[u * 4 + 2] = v.z; eav[u * 4 + 3] = v.w;
      }
      int ob = (ck - 16) * 32 + kq * 8;
#pragma unroll
      for (int j = 0; j < 8; j++) {
        float val = sm.be[ob + j];
#pragma unroll
        for (int i = 0; i < 16; i++) val = fmaf(eav[i], sm.We[i * 64 + ob + j], val);
        sm.u.p1.A[kq * 8 + j][e] = lrelu(val);
      }
    }
    {  // stage Wf1 chunk rows kb..kb+31, 128 cols
#pragma unroll
      for (int j = 0; j < 4; j++) {
        int f = t + j * 256;
        int r = f >> 5, c4 = (f & 31) * 4;
        *(float4*)&sm.u.p1.B[r][c4] = *(const float4*)(Wf1 + (size_t)(kb + r) * 128 + c4);
      }
    }
    __syncthreads();
#pragma unroll 8
    for (int k = 0; k < 32; k++) {
      float4 a4 = *(const float4*)&sm.u.p1.A[k][e0];
      float4 b0 = *(const float4*)&sm.u.p1.B[k][cA];
      float4 b1 = *(const float4*)&sm.u.p1.B[k][cB];
      float av[4] = {a4.x, a4.y, a4.z, a4.w};
      float bv[8] = {b0.x, b0.y, b0.z, b0.w, b1.x, b1.y, b1.z, b1.w};
#pragma unroll
      for (int i = 0; i < 4; i++)
#pragma unroll
        for (int j = 0; j < 8; j++)
          acc[i][j] = fmaf(av[i], bv[j], acc[i][j]);
    }
  }
  __syncthreads();
  // phase 2: T1t[c][e] = lrelu(acc + bf1)
#pragma unroll
  for (int j = 0; j < 4; j++) {
    float bj = bf1[cA + j];
#pragma unroll
    for (int i = 0; i < 4; i++)
      sm.T1t[cA + j][e0 + i] = lrelu(acc[i][j] + bj);
  }
#pragma unroll
  for (int j = 0; j < 4; j++) {
    float bj = bf1[cB + j];
#pragma unroll
    for (int i = 0; i < 4; i++)
      sm.T1t[cB + j][e0 + i] = lrelu(acc[i][4 + j] + bj);
  }
  __syncthreads();
  // phase 3: common[64,64] = T1[64,128] @ Wf2[128,64] + bf2. Wf2 from global (L1-resident).
  const int e0b = (t & 15) * 4, c0b = (t >> 4) * 4;
  float a2[4][4];
#pragma unroll
  for (int j = 0; j < 4; j++) {
    float bj = bf2[c0b + j];
    a2[0][j] = bj; a2[1][j] = bj; a2[2][j] = bj; a2[3][j] = bj;
  }
#pragma unroll 8
  for (int k = 0; k < 128; k++) {
    float4 a4 = *(const float4*)&sm.T1t[k][e0b];
    float4 b4 = *(const float4*)(Wf2g + k * 64 + c0b);
    float av[4] = {a4.x, a4.y, a4.z, a4.w};
    float bv[4] = {b4.x, b4.y, b4.z, b4.w};
#pragma unroll
    for (int i = 0; i < 4; i++)
#pragma unroll
      for (int j = 0; j < 4; j++)
        a2[i][j] = fmaf(av[i], bv[j], a2[i][j]);
  }
#pragma unroll
  for (int i = 0; i < 4; i++) {
    float4 v = {a2[i][0], a2[i][1], a2[i][2], a2[i][3]};
    *(float4*)(common + (size_t)(eb + e0b + i) * 64 + c0b) = v;
  }
}

// ---------------- heads: one wave per edge, weights in registers ----------------
__global__ __launch_bounds__(256, 2) void k_heads(
    const float* __restrict__ common,
    const float* __restrict__ Wc1, const float* __restrict__ bc1,
    const float* __restrict__ Wc2, const float* __restrict__ bc2,
    const float* __restrict__ Wr1, const float* __restrict__ br1,
    const float* __restrict__ Wr2, const float* __restrict__ br2,
    float* __restrict__ out) {
  const int lane = threadIdx.x & 63;
  const int wid = blockIdx.x * 4 + (threadIdx.x >> 6);
  const int nw = gridDim.x * 4;
  // lane o holds column o of Wc1/Wr1 (64 regs each, statically indexed)
  float wc1r[64], wr1r[64];
#pragma unroll
  for (int k = 0; k < 64; k++) {
    wc1r[k] = Wc1[k * 64 + lane];
    wr1r[k] = Wr1[k * 64 + lane];
  }
  const float bc1r = bc1[lane], br1r = br1[lane];
  const float wc2r = Wc2[lane], wr2r = Wr2[lane];
  const float bc2s = bc2[0], br2s = br2[0];
  for (int e = wid; e < N_EDGES; e += nw) {
    float cr = common[(size_t)e * 64 + lane];
    float accC = bc1r, accR = br1r;
#pragma unroll
    for (int k = 0; k < 64; k++) {
      float cv = __shfl(cr, k, 64);
      accC = fmaf(cv, wc1r[k], accC);
      accR = fmaf(cv, wr1r[k], accR);
    }
    float pc = lrelu(accC) * wc2r;
    float pr = lrelu(accR) * wr2r;
#pragma unroll
    for (int off = 32; off > 0; off >>= 1) {
      pc += __shfl_xor(pc, off, 64);
      pr += __shfl_xor(pr, off, 64);
    }
    if (lane == 0) {
      float te = 1.0f / (1.0f + expf(-(pc + bc2s)));
      float tv = pr + br2s;
      out[e] = te * tv;           // final_pred
      out[N_EDGES + e] = te;      // trade_exists
    }
  }
}

extern "C" void kernel_launch(void* const* d_in, const int* in_sizes, int n_in,
                              void* d_out, int out_size, void* d_ws, size_t ws_size,
                              hipStream_t stream) {
  const float* x     = (const float*)d_in[0];
  const int*   eidx  = (const int*)d_in[1];
  const float* eattr = (const float*)d_in[2];
  const float* W1 = (const float*)d_in[3];  const float* b1 = (const float*)d_in[4];
  const float* W2 = (const float*)d_in[5];  const float* b2 = (const float*)d_in[6];
  const float* W3 = (const float*)d_in[7];  const float* b3 = (const float*)d_in[8];
  const float* We = (const float*)d_in[9];  const float* be = (const float*)d_in[10];
  const float* Wf1 = (const float*)d_in[11]; const float* bf1 = (const float*)d_in[12];
  const float* Wf2 = (const float*)d_in[13]; const float* bf2 = (const float*)d_in[14];
  const float* Wc1 = (const float*)d_in[15]; const float* bc1 = (const float*)d_in[16];
  const float* Wc2 = (const float*)d_in[17]; const float* bc2 = (const float*)d_in[18];
  const float* Wr1 = (const float*)d_in[19]; const float* br1 = (const float*)d_in[20];
  const float* Wr2 = (const float*)d_in[21]; const float* br2 = (const float*)d_in[22];
  const int* srcv = eidx;
  const int* dstv = eidx + N_EDGES;
  float* outp = (float*)d_out;

  // workspace arena (floats). Total = 50048 + 44.8M floats ~= 171 MiB.
  float* ws = (float*)d_ws;
  size_t o = 0;
  float* dinv = ws + o; o += 50048;                 // deg -> dinv (in place)
  float* xw1  = ws + o; o += (size_t)N_NODES * 64;
  float* h1   = ws + o; o += (size_t)N_NODES * 64;
  float* xw2  = ws + o; o += (size_t)N_NODES * 128;
  float* h2   = ws + o; o += (size_t)N_NODES * 128;
  float* xw3  = ws + o; o += (size_t)N_NODES * 256;
  float* h3   = ws + o; o += (size_t)N_NODES * 256;
  float* common = xw1;  // aliases dead xw1..xw3 region (25.6M < 32M floats)

  // degree / dinv
  hipMemsetAsync(dinv, 0, N_NODES * sizeof(float), stream);
  k_deg<<<(N_EDGES + 255) / 256, 256, 0, stream>>>(dstv, dinv);
  k_dinv<<<(N_NODES + 255) / 256, 256, 0, stream>>>(dinv);

  // layer 1: 128 -> 64
  k_gemm<<<dim3(391, 1), 256, 0, stream>>>(x, W1, xw1, N_NODES, 128, 64);
  hipMemsetAsync(h1, 0, (size_t)N_NODES * 64 * sizeof(float), stream);
  k_scatter<64><<<(N_EDGES * 16) / 256, 256, 0, stream>>>(xw1, srcv, dstv, dinv, h1);
  k_fin<64><<<(N_NODES * 16) / 256, 256, 0, stream>>>(h1, xw1, dinv, b1);

  // layer 2: 64 -> 128
  k_gemm<<<dim3(391, 2), 256, 0, stream>>>(h1, W2, xw2, N_NODES, 64, 128);
  hipMemsetAsync(h2, 0, (size_t)N_NODES * 128 * sizeof(float), stream);
  k_scatter<128><<<(N_EDGES * 32) / 256, 256, 0, stream>>>(xw2, srcv, dstv, dinv, h2);
  k_fin<128><<<(N_NODES * 32) / 256, 256, 0, stream>>>(h2, xw2, dinv, b2);

  // layer 3: 128 -> 256
  k_gemm<<<dim3(391, 4), 256, 0, stream>>>(h2, W3, xw3, N_NODES, 128, 256);
  hipMemsetAsync(h3, 0, (size_t)N_NODES * 256 * sizeof(float), stream);
  k_scatter<256><<<(N_EDGES * 64) / 256, 256, 0, stream>>>(xw3, srcv, dstv, dinv, h3);
  k_fin<256><<<(N_NODES * 64) / 256, 256, 0, stream>>>(h3, xw3, dinv, b3);

  // fused edge MLP -> common[E,64]
  k_fused<<<N_EDGES / 64, 256, 0, stream>>>(h3, srcv, dstv, eattr, We, be,
                                            Wf1, bf1, Wf2, bf2, common);
  // heads -> (final_pred, trade_exists)
  k_heads<<<768, 256, 0, stream>>>(common, Wc1, bc1, Wc2, bc2, Wr1, br1, Wr2, br2, outp);
}

// Round 9
// 2132.944 us; speedup vs baseline: 2.0112x; 2.0112x over previous
//
#include <hip/hip_runtime.h>
#include <math.h>

// GCN pipeline, fp32 end-to-end (no fp32 MFMA on CDNA4 -> vector FMA).
// Rounds 3-9: CSR gather replaces atomic scatter (atomics were 55% of runtime,
// WRITE_SIZE 4x payload). Self-loop + bias + lrelu folded into gather.
// N=50000 nodes, E=400000 edges, IN=128, H=64.
#define N_NODES 50000
#define N_EDGES 400000

__device__ __forceinline__ float lrelu(float v) { return v > 0.0f ? v : 0.01f * v; }

// ---------------- CSR build ----------------
__global__ __launch_bounds__(256) void k_degi(const int* __restrict__ dstv,
                                              int* __restrict__ degi) {
  int e = blockIdx.x * 256 + threadIdx.x;
  if (e < N_EDGES) atomicAdd(&degi[dstv[e]], 1);
}

// single block 1024 threads: exclusive scan of degi -> rowptr, plus dinv = rsqrt(deg+1)
__global__ __launch_bounds__(1024) void k_scan(const int* __restrict__ degi,
                                               int* __restrict__ rowptr,
                                               float* __restrict__ dinv) {
  __shared__ int swsum[16], swoff[16];
  const int t = threadIdx.x;
  const int lane = t & 63, w = t >> 6;
  int run = 0;
  for (int base = 0; base < N_NODES; base += 1024) {
    int i = base + t;
    int v = (i < N_NODES) ? degi[i] : 0;
    // wave-level inclusive scan
    int x = v;
#pragma unroll
    for (int off = 1; off < 64; off <<= 1) {
      int y = __shfl_up(x, off, 64);
      if (lane >= off) x += y;
    }
    if (lane == 63) swsum[w] = x;
    __syncthreads();
    if (t < 16) {
      int s = swsum[t];
      int si = s;
#pragma unroll
      for (int off = 1; off < 16; off <<= 1) {
        int y = __shfl_up(si, off, 16);
        if (t >= off) si += y;
      }
      swoff[t] = si - s;            // exclusive wave offset
      if (t == 15) swsum[15] = si;  // chunk total
    }
    __syncthreads();
    if (i < N_NODES) {
      rowptr[i] = run + swoff[w] + x - v;
      dinv[i] = rsqrtf((float)(v + 1));  // +1 = self loop
    }
    int tot = swsum[15];
    __syncthreads();
    run += tot;
  }
  if (t == 0) rowptr[N_NODES] = run;
}

__global__ __launch_bounds__(256) void k_slot(const int* __restrict__ srcv,
                                              const int* __restrict__ dstv,
                                              const int* __restrict__ rowptr,
                                              int* __restrict__ cnt,
                                              int* __restrict__ csr_src) {
  int e = blockIdx.x * 256 + threadIdx.x;
  if (e < N_EDGES) {
    int d = dstv[e];
    int pos = rowptr[d] + atomicAdd(&cnt[d], 1);
    csr_src[pos] = srcv[e];
  }
}

// ---------------- fp32 GEMM with row-scale epilogue: xs[r][c] = (A@W)[r][c]*scale[r] ---
// tile 128 rows x 64 cols, KB=32. Thread tile 8r x 4c, rows split {tr*4, 64+tr*4}
// so LDS A-reads are 16B-stride (2-way bank alias = free, m136).
__global__ __launch_bounds__(256, 4) void k_gemm(const float* __restrict__ A,
                                                 const float* __restrict__ W,
                                                 const float* __restrict__ rowscale,
                                                 float* __restrict__ C,
                                                 int M, int K, int Nc) {
  __shared__ float At[32][128];  // [k][r] 16KB
  __shared__ float Bt[32][64];   // [k][c]  8KB
  const int rb = blockIdx.x * 128, cb = blockIdx.y * 64;
  const int t = threadIdx.x;
  const int tr = t & 15, tc = t >> 4;
  const int rA = tr * 4, rB = 64 + tr * 4, c0 = tc * 4;
  float acc[8][4] = {};
  for (int kb = 0; kb < K; kb += 32) {
    __syncthreads();
    {  // stage A: 128 rows x 32 k (transposed)
      int r = t & 127, kq = t >> 7;  // kq in {0,1}
      int row = rb + r; if (row >= M) row = M - 1;
      const float* ap = A + (size_t)row * K + kb + kq * 16;
#pragma unroll
      for (int u = 0; u < 4; u++) {
        float4 v = *(const float4*)(ap + u * 4);
        At[kq * 16 + u * 4 + 0][r] = v.x;
        At[kq * 16 + u * 4 + 1][r] = v.y;
        At[kq * 16 + u * 4 + 2][r] = v.z;
        At[kq * 16 + u * 4 + 3][r] = v.w;
      }
    }
    {  // stage B: 32 k x 64 cols
#pragma unroll
      for (int j = 0; j < 2; j++) {
        int f = t + j * 256;
        int r = f >> 4, c4 = (f & 15) * 4;
        *(float4*)&Bt[r][c4] = *(const float4*)(W + (size_t)(kb + r) * Nc + cb + c4);
      }
    }
    __syncthreads();
#pragma unroll 8
    for (int k = 0; k < 32; k++) {
      float4 a0 = *(const float4*)&At[k][rA];
      float4 a1 = *(const float4*)&At[k][rB];
      float4 b  = *(const float4*)&Bt[k][c0];
      float av[8] = {a0.x, a0.y, a0.z, a0.w, a1.x, a1.y, a1.z, a1.w};
      float bv[4] = {b.x, b.y, b.z, b.w};
#pragma unroll
      for (int i = 0; i < 8; i++)
#pragma unroll
        for (int j = 0; j < 4; j++)
          acc[i][j] = fmaf(av[i], bv[j], acc[i][j]);
    }
  }
#pragma unroll
  for (int i = 0; i < 4; i++) {
    int r = rb + rA + i;
    if (r < M) {
      float sc = rowscale[r];
      float4 v = {acc[i][0] * sc, acc[i][1] * sc, acc[i][2] * sc, acc[i][3] * sc};
      *(float4*)(C + (size_t)r * Nc + cb + c0) = v;
    }
  }
#pragma unroll
  for (int i = 0; i < 4; i++) {
    int r = rb + rB + i;
    if (r < M) {
      float sc = rowscale[r];
      float4 v = {acc[4 + i][0] * sc, acc[4 + i][1] * sc, acc[4 + i][2] * sc, acc[4 + i][3] * sc};
      *(float4*)(C + (size_t)r * Nc + cb + c0) = v;
    }
  }
}

// ---------------- CSR gather: h[d] = lrelu(dinv[d]*(xs[d] + sum_in xs[src]) + b) ----
// xs rows are pre-scaled by dinv[row] in the GEMM epilogue, so per-edge norm
// dinv[s]*dinv[d] = (xs[s] already has dinv[s]) * dinv[d] applied once at the end.
template <int F>
__global__ __launch_bounds__(256) void k_gather(const float* __restrict__ xs,
                                                const int* __restrict__ rowptr,
                                                const int* __restrict__ csr_src,
                                                const float* __restrict__ dinv,
                                                const float* __restrict__ b,
                                                float* __restrict__ h) {
  constexpr int NPB = 256 / F;  // nodes per block (F=64:4, 128:2, 256:1)
  const int node = blockIdx.x * NPB + threadIdx.x / F;
  const int f = threadIdx.x & (F - 1);
  if (node >= N_NODES) return;
  const int beg = rowptr[node], end = rowptr[node + 1];
  float acc = xs[(size_t)node * F + f];  // self-loop term
  int k = beg;
  for (; k + 4 <= end; k += 4) {
    int s0 = csr_src[k], s1 = csr_src[k + 1], s2 = csr_src[k + 2], s3 = csr_src[k + 3];
    float a0 = xs[(size_t)s0 * F + f];
    float a1 = xs[(size_t)s1 * F + f];
    float a2 = xs[(size_t)s2 * F + f];
    float a3 = xs[(size_t)s3 * F + f];
    acc += a0 + a1 + a2 + a3;
  }
  for (; k < end; k++) acc += xs[(size_t)csr_src[k] * F + f];
  h[(size_t)node * F + f] = lrelu(acc * dinv[node] + b[f]);
}

// ---------------- fused edge MLP ----------------
// Per block: 64 edges. Phase1: t1 = combined[64,576] @ Wf1[576,128] via K-chunks of 32,
// gathering h3[src]/h3[dst] and computing edge-encoder cols on the fly.
// Phase2: lrelu(+bf1) -> T1 transposed in LDS. Phase3: common = T1 @ Wf2 + bf2 -> global.
// Output-col split {tc*4, 64+tc*4} keeps phase-1 B-reads at 16B stride (2-way = free).
struct FusedSMem {
  int src[64], dst[64];      // 512 B
  float We[16 * 64];         // 4 KB
  float be[64];              // 256 B
  float T1t[128][68];        // 34 KB, [k][e] transposed, pad 68 -> 2-way phase-3 reads
  union {
    struct { float A[32][64]; float B[32][128]; } p1;  // 8KB + 16KB
  } u;
};  // total 62.75 KB < 64 KB static limit

__global__ __launch_bounds__(256, 2) void k_fused(
    const float* __restrict__ h3, const int* __restrict__ srcv, const int* __restrict__ dstv,
    const float* __restrict__ eattr, const float* __restrict__ Weg, const float* __restrict__ beg_,
    const float* __restrict__ Wf1, const float* __restrict__ bf1,
    const float* __restrict__ Wf2g, const float* __restrict__ bf2,
    float* __restrict__ common) {
  __shared__ FusedSMem sm;
  const int t = threadIdx.x;
  const int eb = blockIdx.x * 64;

  if (t < 64) sm.src[t] = srcv[eb + t];
  else if (t < 128) sm.dst[t - 64] = dstv[eb + t - 64];
  else if (t < 192) sm.be[t - 128] = beg_[t - 128];
  *(float4*)&sm.We[t * 4] = *(const float4*)(Weg + t * 4);  // 1024 floats
  __syncthreads();

  const int te = t & 15, tc = t >> 4;
  const int e0 = te * 4;
  const int cA = tc * 4, cB = 64 + tc * 4;  // split col halves
  float acc[4][8] = {};  // [edge i][col j: j<4 -> cA+j, j>=4 -> cB+(j-4)]

  for (int ck = 0; ck < 18; ck++) {
    __syncthreads();
    const int kb = ck * 32;
    const int e = t & 63, kq = t >> 6;  // 4 threads per edge, 8 k each
    if (ck < 16) {
      // gather h3 rows (src for ck<8, dst for 8<=ck<16)
      int row = (ck < 8) ? sm.src[e] : sm.dst[e];
      int colb = (ck < 8) ? kb : kb - 256;
      const float* p = h3 + (size_t)row * 256 + colb + kq * 8;
      float4 v0 = *(const float4*)p;
      float4 v1 = *(const float4*)(p + 4);
      float* ac = &sm.u.p1.A[kq * 8][0];
      ac[0 * 64 + e] = v0.x; ac[1 * 64 + e] = v0.y; ac[2 * 64 + e] = v0.z; ac[3 * 64 + e] = v0.w;
      ac[4 * 64 + e] = v1.x; ac[5 * 64 + e] = v1.y; ac[6 * 64 + e] = v1.z; ac[7 * 64 + e] = v1.w;
    } else {
      // edge-encoder columns: enc = lrelu(edge_attr @ We + be)
      float eav[16];
      const float* ep = eattr + (size_t)(eb + e) * 16;
#pragma unroll
      for (int u = 0; u < 4; u++) {
        float4 v = *(const float4*)(ep + u * 4);
        eav[u * 4 + 0] = v.x; eav[u * 4 + 1] = v.y; eav[u * 4 + 2] = v.z; eav[u * 4 + 3] = v.w;
      }
      int ob = (ck - 16) * 32 + kq * 8;
#pragma unroll
      for (int j = 0; j < 8; j++) {
        float val = sm.be[ob + j];
#pragma unroll
        for (int i = 0; i < 16; i++) val = fmaf(eav[i], sm.We[i * 64 + ob + j], val);
        sm.u.p1.A[kq * 8 + j][e] = lrelu(val);
      }
    }
    {  // stage Wf1 chunk rows kb..kb+31, 128 cols
#pragma unroll
      for (int j = 0; j < 4; j++) {
        int f = t + j * 256;
        int r = f >> 5, c4 = (f & 31) * 4;
        *(float4*)&sm.u.p1.B[r][c4] = *(const float4*)(Wf1 + (size_t)(kb + r) * 128 + c4);
      }
    }
    __syncthreads();
#pragma unroll 8
    for (int k = 0; k < 32; k++) {
      float4 a4 = *(const float4*)&sm.u.p1.A[k][e0];
      float4 b0 = *(const float4*)&sm.u.p1.B[k][cA];
      float4 b1 = *(const float4*)&sm.u.p1.B[k][cB];
      float av[4] = {a4.x, a4.y, a4.z, a4.w};
      float bv[8] = {b0.x, b0.y, b0.z, b0.w, b1.x, b1.y, b1.z, b1.w};
#pragma unroll
      for (int i = 0; i < 4; i++)
#pragma unroll
        for (int j = 0; j < 8; j++)
          acc[i][j] = fmaf(av[i], bv[j], acc[i][j]);
    }
  }
  __syncthreads();
  // phase 2: T1t[c][e] = lrelu(acc + bf1)
#pragma unroll
  for (int j = 0; j < 4; j++) {
    float bj = bf1[cA + j];
#pragma unroll
    for (int i = 0; i < 4; i++)
      sm.T1t[cA + j][e0 + i] = lrelu(acc[i][j] + bj);
  }
#pragma unroll
  for (int j = 0; j < 4; j++) {
    float bj = bf1[cB + j];
#pragma unroll
    for (int i = 0; i < 4; i++)
      sm.T1t[cB + j][e0 + i] = lrelu(acc[i][4 + j] + bj);
  }
  __syncthreads();
  // phase 3: common[64,64] = T1[64,128] @ Wf2[128,64] + bf2. Wf2 from global (L1-resident).
  const int e0b = (t & 15) * 4, c0b = (t >> 4) * 4;
  float a2[4][4];
#pragma unroll
  for (int j = 0; j < 4; j++) {
    float bj = bf2[c0b + j];
    a2[0][j] = bj; a2[1][j] = bj; a2[2][j] = bj; a2[3][j] = bj;
  }
#pragma unroll 8
  for (int k = 0; k < 128; k++) {
    float4 a4 = *(const float4*)&sm.T1t[k][e0b];
    float4 b4 = *(const float4*)(Wf2g + k * 64 + c0b);
    float av[4] = {a4.x, a4.y, a4.z, a4.w};
    float bv[4] = {b4.x, b4.y, b4.z, b4.w};
#pragma unroll
    for (int i = 0; i < 4; i++)
#pragma unroll
      for (int j = 0; j < 4; j++)
        a2[i][j] = fmaf(av[i], bv[j], a2[i][j]);
  }
#pragma unroll
  for (int i = 0; i < 4; i++) {
    float4 v = {a2[i][0], a2[i][1], a2[i][2], a2[i][3]};
    *(float4*)(common + (size_t)(eb + e0b + i) * 64 + c0b) = v;
  }
}

// ---------------- heads: one wave per edge, weights in registers ----------------
__global__ __launch_bounds__(256, 2) void k_heads(
    const float* __restrict__ common,
    const float* __restrict__ Wc1, const float* __restrict__ bc1,
    const float* __restrict__ Wc2, const float* __restrict__ bc2,
    const float* __restrict__ Wr1, const float* __restrict__ br1,
    const float* __restrict__ Wr2, const float* __restrict__ br2,
    float* __restrict__ out) {
  const int lane = threadIdx.x & 63;
  const int wid = blockIdx.x * 4 + (threadIdx.x >> 6);
  const int nw = gridDim.x * 4;
  // lane o holds column o of Wc1/Wr1 (64 regs each, statically indexed)
  float wc1r[64], wr1r[64];
#pragma unroll
  for (int k = 0; k < 64; k++) {
    wc1r[k] = Wc1[k * 64 + lane];
    wr1r[k] = Wr1[k * 64 + lane];
  }
  const float bc1r = bc1[lane], br1r = br1[lane];
  const float wc2r = Wc2[lane], wr2r = Wr2[lane];
  const float bc2s = bc2[0], br2s = br2[0];
  for (int e = wid; e < N_EDGES; e += nw) {
    float cr = common[(size_t)e * 64 + lane];
    float accC = bc1r, accR = br1r;
#pragma unroll
    for (int k = 0; k < 64; k++) {
      float cv = __shfl(cr, k, 64);
      accC = fmaf(cv, wc1r[k], accC);
      accR = fmaf(cv, wr1r[k], accR);
    }
    float pc = lrelu(accC) * wc2r;
    float pr = lrelu(accR) * wr2r;
#pragma unroll
    for (int off = 32; off > 0; off >>= 1) {
      pc += __shfl_xor(pc, off, 64);
      pr += __shfl_xor(pr, off, 64);
    }
    if (lane == 0) {
      float te = 1.0f / (1.0f + expf(-(pc + bc2s)));
      float tv = pr + br2s;
      out[e] = te * tv;           // final_pred
      out[N_EDGES + e] = te;      // trade_exists
    }
  }
}

extern "C" void kernel_launch(void* const* d_in, const int* in_sizes, int n_in,
                              void* d_out, int out_size, void* d_ws, size_t ws_size,
                              hipStream_t stream) {
  const float* x     = (const float*)d_in[0];
  const int*   eidx  = (const int*)d_in[1];
  const float* eattr = (const float*)d_in[2];
  const float* W1 = (const float*)d_in[3];  const float* b1 = (const float*)d_in[4];
  const float* W2 = (const float*)d_in[5];  const float* b2 = (const float*)d_in[6];
  const float* W3 = (const float*)d_in[7];  const float* b3 = (const float*)d_in[8];
  const float* We = (const float*)d_in[9];  const float* be = (const float*)d_in[10];
  const float* Wf1 = (const float*)d_in[11]; const float* bf1 = (const float*)d_in[12];
  const float* Wf2 = (const float*)d_in[13]; const float* bf2 = (const float*)d_in[14];
  const float* Wc1 = (const float*)d_in[15]; const float* bc1 = (const float*)d_in[16];
  const float* Wc2 = (const float*)d_in[17]; const float* bc2 = (const float*)d_in[18];
  const float* Wr1 = (const float*)d_in[19]; const float* br1 = (const float*)d_in[20];
  const float* Wr2 = (const float*)d_in[21]; const float* br2 = (const float*)d_in[22];
  const int* srcv = eidx;
  const int* dstv = eidx + N_EDGES;
  float* outp = (float*)d_out;

  // ---- workspace arena ----
  // int region: degi[50048] rowptr[50048+pad] cnt[50048] csr_src[400000] -> 550400 ints
  int* ip = (int*)d_ws;
  int* degi    = ip;
  int* rowptr  = ip + 50048;
  int* cnt     = ip + 100096;
  int* csr_src = ip + 150144;  // 400000 -> ends at 550144; pad to 550400
  float* fp = (float*)d_ws + 550400;
  size_t o = 0;
  float* dinv = fp + o; o += 50048;
  float* xs1  = fp + o; o += (size_t)N_NODES * 64;
  float* h1   = fp + o; o += (size_t)N_NODES * 64;
  float* xs2  = fp + o; o += (size_t)N_NODES * 128;
  float* h2   = fp + o; o += (size_t)N_NODES * 128;
  float* xs3  = fp + o; o += (size_t)N_NODES * 256;
  float* h3   = fp + o; o += (size_t)N_NODES * 256;
  float* common = xs1;  // aliases dead xs1..xs3 region (25.6M < 32M floats)

  // ---- CSR build (once, reused by all 3 layers) ----
  hipMemsetAsync(degi, 0, 50048 * sizeof(int), stream);
  hipMemsetAsync(cnt, 0, 50048 * sizeof(int), stream);
  k_degi<<<(N_EDGES + 255) / 256, 256, 0, stream>>>(dstv, degi);
  k_scan<<<1, 1024, 0, stream>>>(degi, rowptr, dinv);
  k_slot<<<(N_EDGES + 255) / 256, 256, 0, stream>>>(srcv, dstv, rowptr, cnt, csr_src);

  // layer 1: 128 -> 64
  k_gemm<<<dim3(391, 1), 256, 0, stream>>>(x, W1, dinv, xs1, N_NODES, 128, 64);
  k_gather<64><<<N_NODES / 4, 256, 0, stream>>>(xs1, rowptr, csr_src, dinv, b1, h1);

  // layer 2: 64 -> 128
  k_gemm<<<dim3(391, 2), 256, 0, stream>>>(h1, W2, dinv, xs2, N_NODES, 64, 128);
  k_gather<128><<<N_NODES / 2, 256, 0, stream>>>(xs2, rowptr, csr_src, dinv, b2, h2);

  // layer 3: 128 -> 256
  k_gemm<<<dim3(391, 4), 256, 0, stream>>>(h2, W3, dinv, xs3, N_NODES, 128, 256);
  k_gather<256><<<N_NODES, 256, 0, stream>>>(xs3, rowptr, csr_src, dinv, b3, h3);

  // fused edge MLP -> common[E,64]
  k_fused<<<N_EDGES / 64, 256, 0, stream>>>(h3, srcv, dstv, eattr, We, be,
                                            Wf1, bf1, Wf2, bf2, common);
  // heads -> (final_pred, trade_exists)
  k_heads<<<768, 256, 0, stream>>>(common, Wc1, bc1, Wc2, bc2, Wr1, br1, Wr2, br2, outp);
}

// Round 12
// 1955.548 us; speedup vs baseline: 2.1936x; 1.0907x over previous
//
#include <hip/hip_runtime.h>
#include <math.h>

// GCN pipeline, fp32 end-to-end (no fp32 MFMA on CDNA4 -> vector FMA).
// R9 measured: CSR design = 2133us total; k_fused = 1347us @ 22.5% occupancy
// (63KB LDS -> 2 blocks/CU), VALUBusy 46%, latency-bound.
// R10-R12 change: union T1t with phase-1 staging buffers (barrier-separated
// lifetimes) -> LDS 63KB -> 38.8KB -> 4 blocks/CU -> 2x TLP.
// N=50000 nodes, E=400000 edges, IN=128, H=64.
#define N_NODES 50000
#define N_EDGES 400000

__device__ __forceinline__ float lrelu(float v) { return v > 0.0f ? v : 0.01f * v; }

// ---------------- CSR build ----------------
__global__ __launch_bounds__(256) void k_degi(const int* __restrict__ dstv,
                                              int* __restrict__ degi) {
  int e = blockIdx.x * 256 + threadIdx.x;
  if (e < N_EDGES) atomicAdd(&degi[dstv[e]], 1);
}

// single block 1024 threads: exclusive scan of degi -> rowptr, plus dinv = rsqrt(deg+1)
__global__ __launch_bounds__(1024) void k_scan(const int* __restrict__ degi,
                                               int* __restrict__ rowptr,
                                               float* __restrict__ dinv) {
  __shared__ int swsum[16], swoff[16];
  const int t = threadIdx.x;
  const int lane = t & 63, w = t >> 6;
  int run = 0;
  for (int base = 0; base < N_NODES; base += 1024) {
    int i = base + t;
    int v = (i < N_NODES) ? degi[i] : 0;
    // wave-level inclusive scan
    int x = v;
#pragma unroll
    for (int off = 1; off < 64; off <<= 1) {
      int y = __shfl_up(x, off, 64);
      if (lane >= off) x += y;
    }
    if (lane == 63) swsum[w] = x;
    __syncthreads();
    if (t < 16) {
      int s = swsum[t];
      int si = s;
#pragma unroll
      for (int off = 1; off < 16; off <<= 1) {
        int y = __shfl_up(si, off, 16);
        if (t >= off) si += y;
      }
      swoff[t] = si - s;            // exclusive wave offset
      if (t == 15) swsum[15] = si;  // chunk total
    }
    __syncthreads();
    if (i < N_NODES) {
      rowptr[i] = run + swoff[w] + x - v;
      dinv[i] = rsqrtf((float)(v + 1));  // +1 = self loop
    }
    int tot = swsum[15];
    __syncthreads();
    run += tot;
  }
  if (t == 0) rowptr[N_NODES] = run;
}

__global__ __launch_bounds__(256) void k_slot(const int* __restrict__ srcv,
                                              const int* __restrict__ dstv,
                                              const int* __restrict__ rowptr,
                                              int* __restrict__ cnt,
                                              int* __restrict__ csr_src) {
  int e = blockIdx.x * 256 + threadIdx.x;
  if (e < N_EDGES) {
    int d = dstv[e];
    int pos = rowptr[d] + atomicAdd(&cnt[d], 1);
    csr_src[pos] = srcv[e];
  }
}

// ---------------- fp32 GEMM with row-scale epilogue: xs[r][c] = (A@W)[r][c]*scale[r] ---
// tile 128 rows x 64 cols, KB=32. Thread tile 8r x 4c, rows split {tr*4, 64+tr*4}
// so LDS A-reads are 16B-stride (2-way bank alias = free, m136).
__global__ __launch_bounds__(256, 4) void k_gemm(const float* __restrict__ A,
                                                 const float* __restrict__ W,
                                                 const float* __restrict__ rowscale,
                                                 float* __restrict__ C,
                                                 int M, int K, int Nc) {
  __shared__ float At[32][128];  // [k][r] 16KB
  __shared__ float Bt[32][64];   // [k][c]  8KB
  const int rb = blockIdx.x * 128, cb = blockIdx.y * 64;
  const int t = threadIdx.x;
  const int tr = t & 15, tc = t >> 4;
  const int rA = tr * 4, rB = 64 + tr * 4, c0 = tc * 4;
  float acc[8][4] = {};
  for (int kb = 0; kb < K; kb += 32) {
    __syncthreads();
    {  // stage A: 128 rows x 32 k (transposed)
      int r = t & 127, kq = t >> 7;  // kq in {0,1}
      int row = rb + r; if (row >= M) row = M - 1;
      const float* ap = A + (size_t)row * K + kb + kq * 16;
#pragma unroll
      for (int u = 0; u < 4; u++) {
        float4 v = *(const float4*)(ap + u * 4);
        At[kq * 16 + u * 4 + 0][r] = v.x;
        At[kq * 16 + u * 4 + 1][r] = v.y;
        At[kq * 16 + u * 4 + 2][r] = v.z;
        At[kq * 16 + u * 4 + 3][r] = v.w;
      }
    }
    {  // stage B: 32 k x 64 cols
#pragma unroll
      for (int j = 0; j < 2; j++) {
        int f = t + j * 256;
        int r = f >> 4, c4 = (f & 15) * 4;
        *(float4*)&Bt[r][c4] = *(const float4*)(W + (size_t)(kb + r) * Nc + cb + c4);
      }
    }
    __syncthreads();
#pragma unroll 8
    for (int k = 0; k < 32; k++) {
      float4 a0 = *(const float4*)&At[k][rA];
      float4 a1 = *(const float4*)&At[k][rB];
      float4 b  = *(const float4*)&Bt[k][c0];
      float av[8] = {a0.x, a0.y, a0.z, a0.w, a1.x, a1.y, a1.z, a1.w};
      float bv[4] = {b.x, b.y, b.z, b.w};
#pragma unroll
      for (int i = 0; i < 8; i++)
#pragma unroll
        for (int j = 0; j < 4; j++)
          acc[i][j] = fmaf(av[i], bv[j], acc[i][j]);
    }
  }
#pragma unroll
  for (int i = 0; i < 4; i++) {
    int r = rb + rA + i;
    if (r < M) {
      float sc = rowscale[r];
      float4 v = {acc[i][0] * sc, acc[i][1] * sc, acc[i][2] * sc, acc[i][3] * sc};
      *(float4*)(C + (size_t)r * Nc + cb + c0) = v;
    }
  }
#pragma unroll
  for (int i = 0; i < 4; i++) {
    int r = rb + rB + i;
    if (r < M) {
      float sc = rowscale[r];
      float4 v = {acc[4 + i][0] * sc, acc[4 + i][1] * sc, acc[4 + i][2] * sc, acc[4 + i][3] * sc};
      *(float4*)(C + (size_t)r * Nc + cb + c0) = v;
    }
  }
}

// ---------------- CSR gather: h[d] = lrelu(dinv[d]*(xs[d] + sum_in xs[src]) + b) ----
// xs rows are pre-scaled by dinv[row] in the GEMM epilogue, so per-edge norm
// dinv[s]*dinv[d] = (xs[s] already has dinv[s]) * dinv[d] applied once at the end.
template <int F>
__global__ __launch_bounds__(256) void k_gather(const float* __restrict__ xs,
                                                const int* __restrict__ rowptr,
                                                const int* __restrict__ csr_src,
                                                const float* __restrict__ dinv,
                                                const float* __restrict__ b,
                                                float* __restrict__ h) {
  constexpr int NPB = 256 / F;  // nodes per block (F=64:4, 128:2, 256:1)
  const int node = blockIdx.x * NPB + threadIdx.x / F;
  const int f = threadIdx.x & (F - 1);
  if (node >= N_NODES) return;
  const int beg = rowptr[node], end = rowptr[node + 1];
  float acc = xs[(size_t)node * F + f];  // self-loop term
  int k = beg;
  for (; k + 4 <= end; k += 4) {
    int s0 = csr_src[k], s1 = csr_src[k + 1], s2 = csr_src[k + 2], s3 = csr_src[k + 3];
    float a0 = xs[(size_t)s0 * F + f];
    float a1 = xs[(size_t)s1 * F + f];
    float a2 = xs[(size_t)s2 * F + f];
    float a3 = xs[(size_t)s3 * F + f];
    acc += a0 + a1 + a2 + a3;
  }
  for (; k < end; k++) acc += xs[(size_t)csr_src[k] * F + f];
  h[(size_t)node * F + f] = lrelu(acc * dinv[node] + b[f]);
}

// ---------------- fused edge MLP ----------------
// Per block: 64 edges. Phase1: t1 = combined[64,576] @ Wf1[576,128] via K-chunks of 32,
// gathering h3[src]/h3[dst] and computing edge-encoder cols on the fly.
// Phase2: lrelu(+bf1) -> T1 transposed in LDS. Phase3: common = T1 @ Wf2 + bf2 -> global.
// R10-R12: T1t UNIONED with phase-1 staging (lifetimes barrier-separated):
// LDS 63KB -> 38.8KB -> 4 blocks/CU (was 2) -> occupancy 22.5% -> ~45%.
struct FusedSMem {
  int src[64], dst[64];      // 512 B
  float We[16 * 64];         // 4 KB
  float be[64];              // 256 B
  union {
    struct { float A[32][64]; float B[32][128]; } p1;  // 24 KB, live phase 1 only
    float T1t[128][68];  // 34 KB, live phases 2-3 only (pad 68 -> 2-way reads)
  } u;
};  // total 38.75 KB -> 4 blocks/CU

__global__ __launch_bounds__(256, 4) void k_fused(
    const float* __restrict__ h3, const int* __restrict__ srcv, const int* __restrict__ dstv,
    const float* __restrict__ eattr, const float* __restrict__ Weg, const float* __restrict__ beg_,
    const float* __restrict__ Wf1, const float* __restrict__ bf1,
    const float* __restrict__ Wf2g, const float* __restrict__ bf2,
    float* __restrict__ common) {
  __shared__ FusedSMem sm;
  const int t = threadIdx.x;
  const int eb = blockIdx.x * 64;

  if (t < 64) sm.src[t] = srcv[eb + t];
  else if (t < 128) sm.dst[t - 64] = dstv[eb + t - 64];
  else if (t < 192) sm.be[t - 128] = beg_[t - 128];
  *(float4*)&sm.We[t * 4] = *(const float4*)(Weg + t * 4);  // 1024 floats
  __syncthreads();

  const int te = t & 15, tc = t >> 4;
  const int e0 = te * 4;
  const int cA = tc * 4, cB = 64 + tc * 4;  // split col halves
  float acc[4][8] = {};  // [edge i][col j: j<4 -> cA+j, j>=4 -> cB+(j-4)]

  for (int ck = 0; ck < 18; ck++) {
    __syncthreads();
    const int kb = ck * 32;
    const int e = t & 63, kq = t >> 6;  // 4 threads per edge, 8 k each
    if (ck < 16) {
      // gather h3 rows (src for ck<8, dst for 8<=ck<16)
      int row = (ck < 8) ? sm.src[e] : sm.dst[e];
      int colb = (ck < 8) ? kb : kb - 256;
      const float* p = h3 + (size_t)row * 256 + colb + kq * 8;
      float4 v0 = *(const float4*)p;
      float4 v1 = *(const float4*)(p + 4);
      float* ac = &sm.u.p1.A[kq * 8][0];
      ac[0 * 64 + e] = v0.x; ac[1 * 64 + e] = v0.y; ac[2 * 64 + e] = v0.z; ac[3 * 64 + e] = v0.w;
      ac[4 * 64 + e] = v1.x; ac[5 * 64 + e] = v1.y; ac[6 * 64 + e] = v1.z; ac[7 * 64 + e] = v1.w;
    } else {
      // edge-encoder columns: enc = lrelu(edge_attr @ We + be)
      float eav[16];
      const float* ep = eattr + (size_t)(eb + e) * 16;
#pragma unroll
      for (int u = 0; u < 4; u++) {
        float4 v = *(const float4*)(ep + u * 4);
        eav[u * 4 + 0] = v.x; eav[u * 4 + 1] = v.y; eav[u * 4 + 2] = v.z; eav[u * 4 + 3] = v.w;
      }
      int ob = (ck - 16) * 32 + kq * 8;
#pragma unroll
      for (int j = 0; j < 8; j++) {
        float val = sm.be[ob + j];
#pragma unroll
        for (int i = 0; i < 16; i++) val = fmaf(eav[i], sm.We[i * 64 + ob + j], val);
        sm.u.p1.A[kq * 8 + j][e] = lrelu(val);
      }
    }
    {  // stage Wf1 chunk rows kb..kb+31, 128 cols
#pragma unroll
      for (int j = 0; j < 4; j++) {
        int f = t + j * 256;
        int r = f >> 5, c4 = (f & 31) * 4;
        *(float4*)&sm.u.p1.B[r][c4] = *(const float4*)(Wf1 + (size_t)(kb + r) * 128 + c4);
      }
    }
    __syncthreads();
#pragma unroll 8
    for (int k = 0; k < 32; k++) {
      float4 a4 = *(const float4*)&sm.u.p1.A[k][e0];
      float4 b0 = *(const float4*)&sm.u.p1.B[k][cA];
      float4 b1 = *(const float4*)&sm.u.p1.B[k][cB];
      float av[4] = {a4.x, a4.y, a4.z, a4.w};
      float bv[8] = {b0.x, b0.y, b0.z, b0.w, b1.x, b1.y, b1.z, b1.w};
#pragma unroll
      for (int i = 0; i < 4; i++)
#pragma unroll
        for (int j = 0; j < 8; j++)
          acc[i][j] = fmaf(av[i], bv[j], acc[i][j]);
    }
  }
  __syncthreads();  // p1 dead from here; T1t becomes live (union safe)
  // phase 2: T1t[c][e] = lrelu(acc + bf1)
#pragma unroll
  for (int j = 0; j < 4; j++) {
    float bj = bf1[cA + j];
#pragma unroll
    for (int i = 0; i < 4; i++)
      sm.u.T1t[cA + j][e0 + i] = lrelu(acc[i][j] + bj);
  }
#pragma unroll
  for (int j = 0; j < 4; j++) {
    float bj = bf1[cB + j];
#pragma unroll
    for (int i = 0; i < 4; i++)
      sm.u.T1t[cB + j][e0 + i] = lrelu(acc[i][4 + j] + bj);
  }
  __syncthreads();
  // phase 3: common[64,64] = T1[64,128] @ Wf2[128,64] + bf2. Wf2 from global (L1-resident).
  const int e0b = (t & 15) * 4, c0b = (t >> 4) * 4;
  float a2[4][4];
#pragma unroll
  for (int j = 0; j < 4; j++) {
    float bj = bf2[c0b + j];
    a2[0][j] = bj; a2[1][j] = bj; a2[2][j] = bj; a2[3][j] = bj;
  }
#pragma unroll 8
  for (int k = 0; k < 128; k++) {
    float4 a4 = *(const float4*)&sm.u.T1t[k][e0b];
    float4 b4 = *(const float4*)(Wf2g + k * 64 + c0b);
    float av[4] = {a4.x, a4.y, a4.z, a4.w};
    float bv[4] = {b4.x, b4.y, b4.z, b4.w};
#pragma unroll
    for (int i = 0; i < 4; i++)
#pragma unroll
      for (int j = 0; j < 4; j++)
        a2[i][j] = fmaf(av[i], bv[j], a2[i][j]);
  }
#pragma unroll
  for (int i = 0; i < 4; i++) {
    float4 v = {a2[i][0], a2[i][1], a2[i][2], a2[i][3]};
    *(float4*)(common + (size_t)(eb + e0b + i) * 64 + c0b) = v;
  }
}

// ---------------- heads: one wave per edge, weights in registers ----------------
__global__ __launch_bounds__(256, 2) void k_heads(
    const float* __restrict__ common,
    const float* __restrict__ Wc1, const float* __restrict__ bc1,
    const float* __restrict__ Wc2, const float* __restrict__ bc2,
    const float* __restrict__ Wr1, const float* __restrict__ br1,
    const float* __restrict__ Wr2, const float* __restrict__ br2,
    float* __restrict__ out) {
  const int lane = threadIdx.x & 63;
  const int wid = blockIdx.x * 4 + (threadIdx.x >> 6);
  const int nw = gridDim.x * 4;
  // lane o holds column o of Wc1/Wr1 (64 regs each, statically indexed)
  float wc1r[64], wr1r[64];
#pragma unroll
  for (int k = 0; k < 64; k++) {
    wc1r[k] = Wc1[k * 64 + lane];
    wr1r[k] = Wr1[k * 64 + lane];
  }
  const float bc1r = bc1[lane], br1r = br1[lane];
  const float wc2r = Wc2[lane], wr2r = Wr2[lane];
  const float bc2s = bc2[0], br2s = br2[0];
  for (int e = wid; e < N_EDGES; e += nw) {
    float cr = common[(size_t)e * 64 + lane];
    float accC = bc1r, accR = br1r;
#pragma unroll
    for (int k = 0; k < 64; k++) {
      float cv = __shfl(cr, k, 64);
      accC = fmaf(cv, wc1r[k], accC);
      accR = fmaf(cv, wr1r[k], accR);
    }
    float pc = lrelu(accC) * wc2r;
    float pr = lrelu(accR) * wr2r;
#pragma unroll
    for (int off = 32; off > 0; off >>= 1) {
      pc += __shfl_xor(pc, off, 64);
      pr += __shfl_xor(pr, off, 64);
    }
    if (lane == 0) {
      float te = 1.0f / (1.0f + expf(-(pc + bc2s)));
      float tv = pr + br2s;
      out[e] = te * tv;           // final_pred
      out[N_EDGES + e] = te;      // trade_exists
    }
  }
}

extern "C" void kernel_launch(void* const* d_in, const int* in_sizes, int n_in,
                              void* d_out, int out_size, void* d_ws, size_t ws_size,
                              hipStream_t stream) {
  const float* x     = (const float*)d_in[0];
  const int*   eidx  = (const int*)d_in[1];
  const float* eattr = (const float*)d_in[2];
  const float* W1 = (const float*)d_in[3];  const float* b1 = (const float*)d_in[4];
  const float* W2 = (const float*)d_in[5];  const float* b2 = (const float*)d_in[6];
  const float* W3 = (const float*)d_in[7];  const float* b3 = (const float*)d_in[8];
  const float* We = (const float*)d_in[9];  const float* be = (const float*)d_in[10];
  const float* Wf1 = (const float*)d_in[11]; const float* bf1 = (const float*)d_in[12];
  const float* Wf2 = (const float*)d_in[13]; const float* bf2 = (const float*)d_in[14];
  const float* Wc1 = (const float*)d_in[15]; const float* bc1 = (const float*)d_in[16];
  const float* Wc2 = (const float*)d_in[17]; const float* bc2 = (const float*)d_in[18];
  const float* Wr1 = (const float*)d_in[19]; const float* br1 = (const float*)d_in[20];
  const float* Wr2 = (const float*)d_in[21]; const float* br2 = (const float*)d_in[22];
  const int* srcv = eidx;
  const int* dstv = eidx + N_EDGES;
  float* outp = (float*)d_out;

  // ---- workspace arena ----
  // int region: degi[50048] rowptr[50048+pad] cnt[50048] csr_src[400000] -> 550400 ints
  int* ip = (int*)d_ws;
  int* degi    = ip;
  int* rowptr  = ip + 50048;
  int* cnt     = ip + 100096;
  int* csr_src = ip + 150144;  // 400000 -> ends at 550144; pad to 550400
  float* fp = (float*)d_ws + 550400;
  size_t o = 0;
  float* dinv = fp + o; o += 50048;
  float* xs1  = fp + o; o += (size_t)N_NODES * 64;
  float* h1   = fp + o; o += (size_t)N_NODES * 64;
  float* xs2  = fp + o; o += (size_t)N_NODES * 128;
  float* h2   = fp + o; o += (size_t)N_NODES * 128;
  float* xs3  = fp + o; o += (size_t)N_NODES * 256;
  float* h3   = fp + o; o += (size_t)N_NODES * 256;
  float* common = xs1;  // aliases dead xs1..xs3 region (25.6M < 32M floats)

  // ---- CSR build (once, reused by all 3 layers) ----
  hipMemsetAsync(degi, 0, 50048 * sizeof(int), stream);
  hipMemsetAsync(cnt, 0, 50048 * sizeof(int), stream);
  k_degi<<<(N_EDGES + 255) / 256, 256, 0, stream>>>(dstv, degi);
  k_scan<<<1, 1024, 0, stream>>>(degi, rowptr, dinv);
  k_slot<<<(N_EDGES + 255) / 256, 256, 0, stream>>>(srcv, dstv, rowptr, cnt, csr_src);

  // layer 1: 128 -> 64
  k_gemm<<<dim3(391, 1), 256, 0, stream>>>(x, W1, dinv, xs1, N_NODES, 128, 64);
  k_gather<64><<<N_NODES / 4, 256, 0, stream>>>(xs1, rowptr, csr_src, dinv, b1, h1);

  // layer 2: 64 -> 128
  k_gemm<<<dim3(391, 2), 256, 0, stream>>>(h1, W2, dinv, xs2, N_NODES, 64, 128);
  k_gather<128><<<N_NODES / 2, 256, 0, stream>>>(xs2, rowptr, csr_src, dinv, b2, h2);

  // layer 3: 128 -> 256
  k_gemm<<<dim3(391, 4), 256, 0, stream>>>(h2, W3, dinv, xs3, N_NODES, 128, 256);
  k_gather<256><<<N_NODES, 256, 0, stream>>>(xs3, rowptr, csr_src, dinv, b3, h3);

  // fused edge MLP -> common[E,64]
  k_fused<<<N_EDGES / 64, 256, 0, stream>>>(h3, srcv, dstv, eattr, We, be,
                                            Wf1, bf1, Wf2, bf2, common);
  // heads -> (final_pred, trade_exists)
  k_heads<<<768, 256, 0, stream>>>(common, Wc1, bc1, Wc2, bc2, Wr1, br1, Wr2, br2, outp);
}